// Round 9
// baseline (1271.425 us; speedup 1.0000x reference)
//
#include <hip/hip_runtime.h>

// CTR-GC block, fp32.  N=64, C=64, T=256, V=25, O=64, R=8.
// kZero: zero the 64 per-n atomic counters.
// kPre : per-(n,c) T-mean -> xm; LAST block of each n (atomic counter) computes adjP.
// kF2  : c-outer x3 accumulation in VGPRs (acc[64]) + per-4-plane adj contraction,
//        coalesced float4 output flush through LDS.

#define N_ 64
#define C_ 64
#define T_ 256
#define V_ 25
#define O_ 64
#define R_ 8

#define TV_ (T_*V_)              // 6400
#define XM_FLOATS (N_*C_*V_)     // 102400
#define ADJ_STRIDE 28            // padded V: rows 112B, float4-aligned
#define ADJ_ROW (V_*ADJ_STRIDE)  // 700 floats per (n,o) plane
#define RV_ (R_*V_)              // 200
#define TT 8
#define OSTEP 4

// ---------------------------------------------------------------- kZero
__global__ void kZero(unsigned int* __restrict__ cnt) {
  if (threadIdx.x < N_) cnt[threadIdx.x] = 0u;
}

// ---------------------------------------------------------------- kPre
__global__ __launch_bounds__(256) void kPre(
    const float* __restrict__ x, float* __restrict__ xm,
    unsigned int* __restrict__ cnt,
    const float* __restrict__ A,
    const float* __restrict__ W1, const float* __restrict__ b1,
    const float* __restrict__ W2, const float* __restrict__ b2,
    const float* __restrict__ W4, const float* __restrict__ b4,
    const float* __restrict__ W5, const float* __restrict__ b5,
    const float* __restrict__ w6p, const float* __restrict__ b6p,
    const float* __restrict__ w7p, const float* __restrict__ b7p,
    float* __restrict__ adjP) {
  __shared__ union {
    struct { float xl[TV_]; float red[4][V_]; } p1;                       // 26.0 KB
    struct { float xmL[C_*V_]; float q1[RV_]; float q2[RV_]; float qm[RV_];
             float dres[R_][V_][V_]; } p2;                                // 28.8 KB
  } u;
  __shared__ int winner;
  const int tid = threadIdx.x;
  const int bid = blockIdx.x;          // n*C + c
  const int n = bid >> 6;

  // ---- phase 1: xm[n,c,:] = mean_t x[n,c,:,:]
  {
    const size_t base = (size_t)bid * TV_;
    const float4* xg = reinterpret_cast<const float4*>(x + base);
    for (int i = tid; i < TV_/4; i += 256) {
      float4 v = xg[i];
      float* dst = &u.p1.xl[4*i];
      dst[0]=v.x; dst[1]=v.y; dst[2]=v.z; dst[3]=v.w;
    }
    __syncthreads();
    float s[V_];
    #pragma unroll
    for (int v = 0; v < V_; ++v) s[v] = u.p1.xl[tid*V_ + v];
    #pragma unroll
    for (int v = 0; v < V_; ++v) {
      #pragma unroll
      for (int off = 32; off >= 1; off >>= 1) s[v] += __shfl_xor(s[v], off);
    }
    const int lane = tid & 63, wv = tid >> 6;
    if (lane == 0) {
      #pragma unroll
      for (int v = 0; v < V_; ++v) u.p1.red[wv][v] = s[v];
    }
    __syncthreads();
    if (tid < V_) {
      float t = u.p1.red[0][tid]+u.p1.red[1][tid]+u.p1.red[2][tid]+u.p1.red[3][tid];
      xm[(size_t)bid * V_ + tid] = t * (1.0f / T_);
    }
  }

  // ---- last-block election (device-scope)
  __threadfence();                  // make xm stores globally visible
  __syncthreads();
  if (tid == 0) {
    unsigned int old = atomicAdd(&cnt[n], 1u);
    winner = (old == C_ - 1u) ? 1 : 0;
  }
  __syncthreads();
  if (!winner) return;
  __threadfence();                  // acquire: other blocks' xm lines

  // ---- phase 2 (winner only): adj for this n
  for (int i = tid; i < C_ * V_; i += 256) u.p2.xmL[i] = xm[(size_t)n * C_ * V_ + i];
  __syncthreads();

  for (int i = tid; i < 3 * RV_; i += 256) {
    const int which = i / RV_, rem = i % RV_;
    const int r = rem / V_, v = rem % V_;
    const float* W = (which == 0) ? W1 : (which == 1) ? W2 : W5;
    const float* b = (which == 0) ? b1 : (which == 1) ? b2 : b5;
    float s = b[r];
    for (int c = 0; c < C_; ++c) s += W[r * C_ + c] * u.p2.xmL[c * V_ + v];
    float* P = (which == 0) ? u.p2.q1 : (which == 1) ? u.p2.q2 : u.p2.qm;
    P[rem] = s;
  }
  __syncthreads();

  if (tid < RV_) {
    const int r = tid / V_, uu = tid % V_;
    const float w6 = w6p[0], b6 = b6p[0], w7 = w7p[0], b7 = b7p[0];
    const float qu = w6 * u.p2.qm[r * V_ + uu] + b6;
    float e[V_];
    float mx = -INFINITY;
    #pragma unroll
    for (int v = 0; v < V_; ++v) {
      float a = 5.0f * qu * (w7 * u.p2.qm[r * V_ + v] + b7);
      e[v] = a;
      mx = fmaxf(mx, a);
    }
    float ssum = 0.f;
    #pragma unroll
    for (int v = 0; v < V_; ++v) { float ev = expf(e[v] - mx); e[v] = ev; ssum += ev; }
    const float inv = 1.0f / ssum;
    const float q1u = u.p2.q1[r * V_ + uu];
    #pragma unroll
    for (int v = 0; v < V_; ++v) {
      float res = tanhf(e[v] * inv);
      float dv  = tanhf(q1u - u.p2.q2[r * V_ + v]);
      u.p2.dres[r][uu][v] = dv + res;
    }
  }
  __syncthreads();

  for (int i = tid; i < O_ * V_; i += 256) {
    const int o = i / V_, uu = i % V_;
    const float b4o2 = 2.0f * b4[o];
    float w4r[R_];
    #pragma unroll
    for (int r = 0; r < R_; ++r) w4r[r] = W4[o * R_ + r];
    float* dst = adjP + (size_t)(n * O_ + o) * ADJ_ROW + (size_t)uu * ADJ_STRIDE;
    #pragma unroll
    for (int v = 0; v < V_; ++v) {
      float s = b4o2 + A[uu * V_ + v];
      #pragma unroll
      for (int r = 0; r < R_; ++r) s += w4r[r] * u.p2.dres[r][uu][v];
      dst[v] = s;
    }
  }
}

// ---------------------------------------------------------------- kF2
// block = (t-tile of 8, n), 256 threads: thread = (t = tid>>5, vp = tid&31).
// Phase A (barrier-free): acc[o] = sum_c W3[o][c] * x[n,c,t,vp]  (x read ONCE).
// Phase B (x16, unrolled): stage 4 adj planes -> LDS, x3 row-swap via LDS,
//   contraction, transpose-flush with aligned float4 stores.
__global__ __launch_bounds__(256, 4) void kF2(
    const float* __restrict__ x, const float* __restrict__ W3,
    const float* __restrict__ b3, const float* __restrict__ adjP,
    float* __restrict__ out) {
  __shared__ __align__(16) float W3T[C_ * O_];            // [c][o], 16 KB
  __shared__ __align__(16) float adjL[OSTEP][ADJ_ROW];    // 11.2 KB
  __shared__ float x3L[OSTEP][TT][32];                    // 4 KB
  __shared__ float oL[OSTEP][TT][26];                     // 3.25 KB (stride 26)
  const int tid = threadIdx.x;
  const int t  = tid >> 5;
  const int vp = tid & 31;
  const int n  = blockIdx.y;
  const int t0 = blockIdx.x * TT;
  const size_t nbase = (size_t)n * C_ * TV_;
  const int vclamp = (vp < V_) ? vp : (V_ - 1);
  const int col = (t0 + t) * V_ + vclamp;
  const bool active_u = (vp < V_);

  // one-time W3 transpose into LDS (coalesced read; scatter write is one-time cost)
  for (int i = tid; i < C_ * O_; i += 256) {
    const int o = i >> 6, c = i & 63;
    W3T[c * O_ + o] = W3[i];
  }
  __syncthreads();

  // ---- phase A: accumulators (must stay in VGPRs — computed state)
  float acc[O_];
  #pragma unroll
  for (int o = 0; o < O_; ++o) acc[o] = 0.f;
  #pragma unroll 4
  for (int c = 0; c < C_; ++c) {
    const float xc = x[nbase + (size_t)c * TV_ + col];
    const float4* wrow = reinterpret_cast<const float4*>(&W3T[c * O_]);  // broadcast
    #pragma unroll
    for (int j = 0; j < O_/4; ++j) {
      float4 wv = wrow[j];
      acc[4*j+0] += wv.x * xc;
      acc[4*j+1] += wv.y * xc;
      acc[4*j+2] += wv.z * xc;
      acc[4*j+3] += wv.w * xc;
    }
  }

  const float* adjN = adjP + (size_t)n * O_ * ADJ_ROW;
  float* outN = out + nbase;

  // ---- phase B: 16 groups of 4 output planes (fully unrolled: static acc idx)
  #pragma unroll
  for (int op = 0; op < O_; op += OSTEP) {
    if (tid < ADJ_ROW / 4) {
      #pragma unroll
      for (int k = 0; k < OSTEP; ++k) {
        float4 a = reinterpret_cast<const float4*>(adjN + (size_t)(op + k) * ADJ_ROW)[tid];
        reinterpret_cast<float4*>(&adjL[k][0])[tid] = a;
      }
    }
    #pragma unroll
    for (int k = 0; k < OSTEP; ++k)
      x3L[k][t][vp] = acc[op + k] + b3[op + k];
    __syncthreads();                                   // B1: stage ready
    #pragma unroll
    for (int k = 0; k < OSTEP; ++k) {
      const float* ar = &adjL[k][(active_u ? vp : 0) * ADJ_STRIDE];
      const float* xr = &x3L[k][t][0];
      float s = 0.f;
      #pragma unroll
      for (int j = 0; j < 6; ++j) {
        float4 av = *reinterpret_cast<const float4*>(ar + 4 * j);
        float4 xw = *reinterpret_cast<const float4*>(xr + 4 * j);
        s += av.x * xw.x + av.y * xw.y + av.z * xw.z + av.w * xw.w;
      }
      s += ar[24] * xr[24];
      if (active_u) oL[k][t][vp] = s;
    }
    __syncthreads();                                   // B2: oL complete
    // coalesced flush: per plane the tile is TT*V = 200 floats = 50 float4.
    // 4 planes x 50 float4 = 200 lanes, one pass.  (R8 crash fix: was 200/plane.)
    if (tid < OSTEP * 50) {
      const int p = tid / 50, rem = tid - p * 50;
      const int e = rem * 4;
      float4 vv;
      vv.x = oL[p][(e    ) / V_][(e    ) % V_];
      vv.y = oL[p][(e + 1) / V_][(e + 1) % V_];
      vv.z = oL[p][(e + 2) / V_][(e + 2) % V_];
      vv.w = oL[p][(e + 3) / V_][(e + 3) % V_];
      reinterpret_cast<float4*>(outN + (size_t)(op + p) * TV_ + (size_t)t0 * V_)[rem] = vv;
    }
    __syncthreads();                                   // B3: flush reads done
  }
}

// ---------------------------------------------------------------- launch
extern "C" void kernel_launch(void* const* d_in, const int* in_sizes, int n_in,
                              void* d_out, int out_size, void* d_ws, size_t ws_size,
                              hipStream_t stream) {
  const float* x  = (const float*)d_in[0];
  const float* A  = (const float*)d_in[1];
  const float* W1 = (const float*)d_in[2];
  const float* b1 = (const float*)d_in[3];
  const float* W2 = (const float*)d_in[4];
  const float* b2 = (const float*)d_in[5];
  const float* W3 = (const float*)d_in[6];
  const float* b3 = (const float*)d_in[7];
  const float* W4 = (const float*)d_in[8];
  const float* b4 = (const float*)d_in[9];
  const float* W5 = (const float*)d_in[10];
  const float* b5 = (const float*)d_in[11];
  const float* w6 = (const float*)d_in[12];
  const float* b6 = (const float*)d_in[13];
  const float* w7 = (const float*)d_in[14];
  const float* b7 = (const float*)d_in[15];
  float* out = (float*)d_out;

  float* xm = (float*)d_ws;                                  // 102400 f
  unsigned int* cnt = (unsigned int*)((char*)d_ws + XM_FLOATS * 4);  // 64 u32 (pad to 256B)
  float* adjP = (float*)((char*)d_ws + XM_FLOATS * 4 + 256); // 2,867,200 f; 16B-aligned

  kZero<<<dim3(1), 64, 0, stream>>>(cnt);
  kPre<<<dim3(N_ * C_), 256, 0, stream>>>(x, xm, cnt, A, W1, b1, W2, b2,
                                          W4, b4, W5, b5, w6, b6, w7, b7, adjP);
  kF2<<<dim3(T_ / TT, N_), 256, 0, stream>>>(x, W3, b3, adjP, out);
}

// Round 12
// 560.216 us; speedup vs baseline: 2.2695x; 2.2695x over previous
//
#include <hip/hip_runtime.h>

// CTR-GC block, fp32.  N=64, C=64, T=256, V=25, O=64, R=8.
// k1_mean (xm = mean_t x) -> k2_adj (adj, padded rows) -> kF2 (fused x3 + contraction).
// R9 lesson: NO cross-block fences/atomics — device-scope fences flush per-XCD L2
// on CDNA4 and stalled the whole GPU (845us at 1% BW). Kernel boundaries instead.

#define N_ 64
#define C_ 64
#define T_ 256
#define V_ 25
#define O_ 64
#define R_ 8

#define TV_ (T_*V_)              // 6400
#define XM_FLOATS (N_*C_*V_)     // 102400
#define ADJ_STRIDE 28            // padded V: rows 112B, float4-aligned
#define ADJ_ROW (V_*ADJ_STRIDE)  // 700 floats per (n,o) plane
#define RV_ (R_*V_)              // 200
#define TT 8
#define OSTEP 4

// ---------------------------------------------------------------- k1: xm = mean_t x
__global__ __launch_bounds__(256) void k1_mean(const float* __restrict__ x,
                                               float* __restrict__ xm) {
  __shared__ float xl[TV_];        // 25.6 KB
  __shared__ float red[4][V_];
  const int tid = threadIdx.x;
  const size_t base = (size_t)blockIdx.x * TV_;   // blockIdx.x = n*C + c
  const float4* xg = reinterpret_cast<const float4*>(x + base);
  for (int i = tid; i < TV_/4; i += 256) {
    float4 v = xg[i];
    float* dst = &xl[4*i];
    dst[0]=v.x; dst[1]=v.y; dst[2]=v.z; dst[3]=v.w;
  }
  __syncthreads();
  float s[V_];
  #pragma unroll
  for (int v = 0; v < V_; ++v) s[v] = xl[tid*V_ + v];
  #pragma unroll
  for (int v = 0; v < V_; ++v) {
    #pragma unroll
    for (int off = 32; off >= 1; off >>= 1) s[v] += __shfl_xor(s[v], off);
  }
  const int lane = tid & 63, w = tid >> 6;
  if (lane == 0) {
    #pragma unroll
    for (int v = 0; v < V_; ++v) red[w][v] = s[v];
  }
  __syncthreads();
  if (tid < V_) {
    float t = red[0][tid] + red[1][tid] + red[2][tid] + red[3][tid];
    xm[(size_t)blockIdx.x * V_ + tid] = t * (1.0f / T_);
  }
}

// ---------------------------------------------------------------- k2: adj (padded rows)
__global__ __launch_bounds__(256) void k2_adj(
    const float* __restrict__ xm, const float* __restrict__ A,
    const float* __restrict__ W1, const float* __restrict__ b1,
    const float* __restrict__ W2, const float* __restrict__ b2,
    const float* __restrict__ W4, const float* __restrict__ b4,
    const float* __restrict__ W5, const float* __restrict__ b5,
    const float* __restrict__ w6p, const float* __restrict__ b6p,
    const float* __restrict__ w7p, const float* __restrict__ b7p,
    float* __restrict__ adjP) {
  __shared__ float xmL[C_ * V_];
  __shared__ float p1[RV_];
  __shared__ float p2[RV_];
  __shared__ float pm[RV_];
  __shared__ float dres[R_][V_][V_];
  const int n = blockIdx.x, tid = threadIdx.x;

  for (int i = tid; i < C_ * V_; i += 256) xmL[i] = xm[(size_t)n * C_ * V_ + i];
  __syncthreads();

  for (int i = tid; i < 3 * RV_; i += 256) {
    const int which = i / RV_, rem = i % RV_;
    const int r = rem / V_, v = rem % V_;
    const float* W = (which == 0) ? W1 : (which == 1) ? W2 : W5;
    const float* b = (which == 0) ? b1 : (which == 1) ? b2 : b5;
    float s = b[r];
    for (int c = 0; c < C_; ++c) s += W[r * C_ + c] * xmL[c * V_ + v];
    float* P = (which == 0) ? p1 : (which == 1) ? p2 : pm;
    P[rem] = s;
  }
  __syncthreads();

  if (tid < RV_) {
    const int r = tid / V_, u = tid % V_;
    const float w6 = w6p[0], b6 = b6p[0], w7 = w7p[0], b7 = b7p[0];
    const float qu = w6 * pm[r * V_ + u] + b6;
    float e[V_];
    float mx = -INFINITY;
    #pragma unroll
    for (int v = 0; v < V_; ++v) {
      float a = 5.0f * qu * (w7 * pm[r * V_ + v] + b7);
      e[v] = a;
      mx = fmaxf(mx, a);
    }
    float ssum = 0.f;
    #pragma unroll
    for (int v = 0; v < V_; ++v) { float ev = expf(e[v] - mx); e[v] = ev; ssum += ev; }
    const float inv = 1.0f / ssum;
    const float p1u = p1[r * V_ + u];
    #pragma unroll
    for (int v = 0; v < V_; ++v) {
      float res = tanhf(e[v] * inv);
      float dv  = tanhf(p1u - p2[r * V_ + v]);
      dres[r][u][v] = dv + res;
    }
  }
  __syncthreads();

  for (int i = tid; i < O_ * V_; i += 256) {
    const int o = i / V_, u = i % V_;
    const float b4o2 = 2.0f * b4[o];
    float w4r[R_];
    #pragma unroll
    for (int r = 0; r < R_; ++r) w4r[r] = W4[o * R_ + r];
    float* dst = adjP + (size_t)(n * O_ + o) * ADJ_ROW + (size_t)u * ADJ_STRIDE;
    #pragma unroll
    for (int v = 0; v < V_; ++v) {
      float s = b4o2 + A[u * V_ + v];
      #pragma unroll
      for (int r = 0; r < R_; ++r) s += w4r[r] * dres[r][u][v];
      dst[v] = s;
    }
  }
}

// ---------------------------------------------------------------- kF2
// block = (t-tile of 8, n), 256 threads: thread = (t = tid>>5, vp = tid&31).
// Phase A (barrier-free): acc[o] = sum_c W3[o][c] * x[n,c,t,vp]  (x read ONCE).
// Phase B (x16, unrolled): stage 4 adj planes -> LDS, x3 row-swap via LDS,
//   contraction, transpose-flush with aligned float4 stores.
__global__ __launch_bounds__(256, 4) void kF2(
    const float* __restrict__ x, const float* __restrict__ W3,
    const float* __restrict__ b3, const float* __restrict__ adjP,
    float* __restrict__ out) {
  __shared__ __align__(16) float W3T[C_ * O_];            // [c][o], 16 KB
  __shared__ __align__(16) float adjL[OSTEP][ADJ_ROW];    // 11.2 KB
  __shared__ float x3L[OSTEP][TT][32];                    // 4 KB
  __shared__ float oL[OSTEP][TT][26];                     // 3.25 KB (stride 26)
  const int tid = threadIdx.x;
  const int t  = tid >> 5;
  const int vp = tid & 31;
  const int n  = blockIdx.y;
  const int t0 = blockIdx.x * TT;
  const size_t nbase = (size_t)n * C_ * TV_;
  const int vclamp = (vp < V_) ? vp : (V_ - 1);
  const int col = (t0 + t) * V_ + vclamp;
  const bool active_u = (vp < V_);

  // one-time W3 transpose into LDS (coalesced read; scatter write is one-time cost)
  for (int i = tid; i < C_ * O_; i += 256) {
    const int o = i >> 6, c = i & 63;
    W3T[c * O_ + o] = W3[i];
  }
  __syncthreads();

  // ---- phase A: accumulators (must stay in VGPRs — computed state)
  float acc[O_];
  #pragma unroll
  for (int o = 0; o < O_; ++o) acc[o] = 0.f;
  #pragma unroll 4
  for (int c = 0; c < C_; ++c) {
    const float xc = x[nbase + (size_t)c * TV_ + col];
    const float4* wrow = reinterpret_cast<const float4*>(&W3T[c * O_]);  // broadcast
    #pragma unroll
    for (int j = 0; j < O_/4; ++j) {
      float4 wv = wrow[j];
      acc[4*j+0] += wv.x * xc;
      acc[4*j+1] += wv.y * xc;
      acc[4*j+2] += wv.z * xc;
      acc[4*j+3] += wv.w * xc;
    }
  }

  const float* adjN = adjP + (size_t)n * O_ * ADJ_ROW;
  float* outN = out + nbase;

  // ---- phase B: 16 groups of 4 output planes (fully unrolled: static acc idx)
  #pragma unroll
  for (int op = 0; op < O_; op += OSTEP) {
    if (tid < ADJ_ROW / 4) {
      #pragma unroll
      for (int k = 0; k < OSTEP; ++k) {
        float4 a = reinterpret_cast<const float4*>(adjN + (size_t)(op + k) * ADJ_ROW)[tid];
        reinterpret_cast<float4*>(&adjL[k][0])[tid] = a;
      }
    }
    #pragma unroll
    for (int k = 0; k < OSTEP; ++k)
      x3L[k][t][vp] = acc[op + k] + b3[op + k];
    __syncthreads();                                   // B1: stage ready
    #pragma unroll
    for (int k = 0; k < OSTEP; ++k) {
      const float* ar = &adjL[k][(active_u ? vp : 0) * ADJ_STRIDE];
      const float* xr = &x3L[k][t][0];
      float s = 0.f;
      #pragma unroll
      for (int j = 0; j < 6; ++j) {
        float4 av = *reinterpret_cast<const float4*>(ar + 4 * j);
        float4 xw = *reinterpret_cast<const float4*>(xr + 4 * j);
        s += av.x * xw.x + av.y * xw.y + av.z * xw.z + av.w * xw.w;
      }
      s += ar[24] * xr[24];
      if (active_u) oL[k][t][vp] = s;
    }
    __syncthreads();                                   // B2: oL complete
    // coalesced flush: per plane the tile is TT*V = 200 floats = 50 float4.
    if (tid < OSTEP * 50) {
      const int p = tid / 50, rem = tid - p * 50;
      const int e = rem * 4;
      float4 vv;
      vv.x = oL[p][(e    ) / V_][(e    ) % V_];
      vv.y = oL[p][(e + 1) / V_][(e + 1) % V_];
      vv.z = oL[p][(e + 2) / V_][(e + 2) % V_];
      vv.w = oL[p][(e + 3) / V_][(e + 3) % V_];
      reinterpret_cast<float4*>(outN + (size_t)(op + p) * TV_ + (size_t)t0 * V_)[rem] = vv;
    }
    __syncthreads();                                   // B3: flush reads done
  }
}

// ---------------------------------------------------------------- launch
extern "C" void kernel_launch(void* const* d_in, const int* in_sizes, int n_in,
                              void* d_out, int out_size, void* d_ws, size_t ws_size,
                              hipStream_t stream) {
  const float* x  = (const float*)d_in[0];
  const float* A  = (const float*)d_in[1];
  const float* W1 = (const float*)d_in[2];
  const float* b1 = (const float*)d_in[3];
  const float* W2 = (const float*)d_in[4];
  const float* b2 = (const float*)d_in[5];
  const float* W3 = (const float*)d_in[6];
  const float* b3 = (const float*)d_in[7];
  const float* W4 = (const float*)d_in[8];
  const float* b4 = (const float*)d_in[9];
  const float* W5 = (const float*)d_in[10];
  const float* b5 = (const float*)d_in[11];
  const float* w6 = (const float*)d_in[12];
  const float* b6 = (const float*)d_in[13];
  const float* w7 = (const float*)d_in[14];
  const float* b7 = (const float*)d_in[15];
  float* out = (float*)d_out;

  float* xm   = (float*)d_ws;            // 102,400 f = 0.41 MB
  float* adjP = xm + XM_FLOATS;          // 64*64*700 f = 11.5 MB

  k1_mean<<<dim3(N_ * C_), 256, 0, stream>>>(x, xm);
  k2_adj<<<dim3(N_), 256, 0, stream>>>(xm, A, W1, b1, W2, b2, W4, b4, W5, b5,
                                       w6, b6, w7, b7, adjP);
  kF2<<<dim3(T_ / TT, N_), 256, 0, stream>>>(x, W3, b3, adjP, out);
}

// Round 13
// 380.507 us; speedup vs baseline: 3.3414x; 1.4723x over previous
//
#include <hip/hip_runtime.h>

// CTR-GC block, fp32.  N=64, C=64, T=256, V=25, O=64, R=8.
// k1_mean -> k2_adj -> kF2.
// R9 : no cross-block fences (per-XCD L2 flush catastrophe).
// R12: kF2 spilled acc[64] (VGPR clamped 64, WRITE 858MB) + 4-way adjL bank
//      conflict (stride-28 rows). Fixes: launch_bounds(256,2), W3 via scalar
//      K$ loads (no LDS), phase-B remap u=tid>>3/t=tid&7, x3L stride 36.

#define N_ 64
#define C_ 64
#define T_ 256
#define V_ 25
#define O_ 64
#define R_ 8

#define TV_ (T_*V_)              // 6400
#define XM_FLOATS (N_*C_*V_)     // 102400
#define ADJ_STRIDE 28            // padded V: rows 112B, float4-aligned
#define ADJ_ROW (V_*ADJ_STRIDE)  // 700 floats per (n,o) plane
#define RV_ (R_*V_)              // 200
#define TT 8
#define OSTEP 4
#define X3S 36                   // x3L row stride: 9 quads -> distinct quad per t

// ---------------------------------------------------------------- k1: xm = mean_t x
__global__ __launch_bounds__(256) void k1_mean(const float* __restrict__ x,
                                               float* __restrict__ xm) {
  __shared__ float xl[TV_];        // 25.6 KB
  __shared__ float red[4][V_];
  const int tid = threadIdx.x;
  const size_t base = (size_t)blockIdx.x * TV_;   // blockIdx.x = n*C + c
  const float4* xg = reinterpret_cast<const float4*>(x + base);
  for (int i = tid; i < TV_/4; i += 256) {
    float4 v = xg[i];
    float* dst = &xl[4*i];
    dst[0]=v.x; dst[1]=v.y; dst[2]=v.z; dst[3]=v.w;
  }
  __syncthreads();
  float s[V_];
  #pragma unroll
  for (int v = 0; v < V_; ++v) s[v] = xl[tid*V_ + v];
  #pragma unroll
  for (int v = 0; v < V_; ++v) {
    #pragma unroll
    for (int off = 32; off >= 1; off >>= 1) s[v] += __shfl_xor(s[v], off);
  }
  const int lane = tid & 63, w = tid >> 6;
  if (lane == 0) {
    #pragma unroll
    for (int v = 0; v < V_; ++v) red[w][v] = s[v];
  }
  __syncthreads();
  if (tid < V_) {
    float t = red[0][tid] + red[1][tid] + red[2][tid] + red[3][tid];
    xm[(size_t)blockIdx.x * V_ + tid] = t * (1.0f / T_);
  }
}

// ---------------------------------------------------------------- k2: adj (padded rows)
__global__ __launch_bounds__(256) void k2_adj(
    const float* __restrict__ xm, const float* __restrict__ A,
    const float* __restrict__ W1, const float* __restrict__ b1,
    const float* __restrict__ W2, const float* __restrict__ b2,
    const float* __restrict__ W4, const float* __restrict__ b4,
    const float* __restrict__ W5, const float* __restrict__ b5,
    const float* __restrict__ w6p, const float* __restrict__ b6p,
    const float* __restrict__ w7p, const float* __restrict__ b7p,
    float* __restrict__ adjP) {
  __shared__ float xmL[C_ * V_];
  __shared__ float p1[RV_];
  __shared__ float p2[RV_];
  __shared__ float pm[RV_];
  __shared__ float dres[R_][V_][V_];
  const int n = blockIdx.x, tid = threadIdx.x;

  for (int i = tid; i < C_ * V_; i += 256) xmL[i] = xm[(size_t)n * C_ * V_ + i];
  __syncthreads();

  for (int i = tid; i < 3 * RV_; i += 256) {
    const int which = i / RV_, rem = i % RV_;
    const int r = rem / V_, v = rem % V_;
    const float* W = (which == 0) ? W1 : (which == 1) ? W2 : W5;
    const float* b = (which == 0) ? b1 : (which == 1) ? b2 : b5;
    float s = b[r];
    for (int c = 0; c < C_; ++c) s += W[r * C_ + c] * xmL[c * V_ + v];
    float* P = (which == 0) ? p1 : (which == 1) ? p2 : pm;
    P[rem] = s;
  }
  __syncthreads();

  if (tid < RV_) {
    const int r = tid / V_, u = tid % V_;
    const float w6 = w6p[0], b6 = b6p[0], w7 = w7p[0], b7 = b7p[0];
    const float qu = w6 * pm[r * V_ + u] + b6;
    float e[V_];
    float mx = -INFINITY;
    #pragma unroll
    for (int v = 0; v < V_; ++v) {
      float a = 5.0f * qu * (w7 * pm[r * V_ + v] + b7);
      e[v] = a;
      mx = fmaxf(mx, a);
    }
    float ssum = 0.f;
    #pragma unroll
    for (int v = 0; v < V_; ++v) { float ev = expf(e[v] - mx); e[v] = ev; ssum += ev; }
    const float inv = 1.0f / ssum;
    const float p1u = p1[r * V_ + u];
    #pragma unroll
    for (int v = 0; v < V_; ++v) {
      float res = tanhf(e[v] * inv);
      float dv  = tanhf(p1u - p2[r * V_ + v]);
      dres[r][u][v] = dv + res;
    }
  }
  __syncthreads();

  for (int i = tid; i < O_ * V_; i += 256) {
    const int o = i / V_, u = i % V_;
    const float b4o2 = 2.0f * b4[o];
    float w4r[R_];
    #pragma unroll
    for (int r = 0; r < R_; ++r) w4r[r] = W4[o * R_ + r];
    float* dst = adjP + (size_t)(n * O_ + o) * ADJ_ROW + (size_t)u * ADJ_STRIDE;
    #pragma unroll
    for (int v = 0; v < V_; ++v) {
      float s = b4o2 + A[u * V_ + v];
      #pragma unroll
      for (int r = 0; r < R_; ++r) s += w4r[r] * dres[r][u][v];
      dst[v] = s;
    }
  }
}

// ---------------------------------------------------------------- kF2
// block = (t-tile of 8, n), 256 threads.
// Phase A: thread (t=tid>>5, vp=tid&31): acc[o] += W3[o][c]*x col, W3 via
//          wave-uniform GLOBAL scalar loads (K$ path, no LDS).
// Phase B: remap (u=tid>>3, t=tid&7): adjL rows broadcast per 8-lane group,
//          conflict-free quads; x3L stride 36 -> distinct quad per t.
__global__ __launch_bounds__(256, 2) void kF2(
    const float* __restrict__ x, const float* __restrict__ W3,
    const float* __restrict__ b3, const float* __restrict__ adjP,
    float* __restrict__ out) {
  __shared__ __align__(16) float adjL[OSTEP][ADJ_ROW];    // 11.2 KB
  __shared__ __align__(16) float x3L[OSTEP][TT][X3S];     // 4.6 KB
  __shared__ float oL[OSTEP][TT][26];                     // 3.25 KB
  const int tid = threadIdx.x;
  const int t  = tid >> 5;          // phase-A row
  const int vp = tid & 31;          // phase-A col (25..31 pad)
  const int n  = blockIdx.y;
  const int t0 = blockIdx.x * TT;
  const size_t nbase = (size_t)n * C_ * TV_;
  const int vclamp = (vp < V_) ? vp : (V_ - 1);
  const int col = (t0 + t) * V_ + vclamp;

  // ---- phase A: acc[64] in VGPRs; W3 through scalar pipe
  float acc[O_];
  #pragma unroll
  for (int o = 0; o < O_; ++o) acc[o] = 0.f;
  for (int c = 0; c < C_; ++c) {
    const float xc = x[nbase + (size_t)c * TV_ + col];
    const float* wc = W3 + c;                    // W3[o*C_+c], wave-uniform
    #pragma unroll
    for (int o = 0; o < O_; ++o)
      acc[o] += wc[o * C_] * xc;                 // s_load + v_fmac
  }

  const float* adjN = adjP + (size_t)n * O_ * ADJ_ROW;
  float* outN = out + nbase;

  // ---- phase B mapping
  const int u  = tid >> 3;          // 0..31 (25..31 inactive)
  const int t2 = tid & 7;           // 0..7
  const bool act = (u < V_);
  const int uc = act ? u : 0;

  #pragma unroll
  for (int op = 0; op < O_; op += OSTEP) {
    if (tid < ADJ_ROW / 4) {        // 175 lanes stage 4 adj planes
      #pragma unroll
      for (int k = 0; k < OSTEP; ++k) {
        float4 a = reinterpret_cast<const float4*>(adjN + (size_t)(op + k) * ADJ_ROW)[tid];
        reinterpret_cast<float4*>(&adjL[k][0])[tid] = a;
      }
    }
    #pragma unroll
    for (int k = 0; k < OSTEP; ++k)
      x3L[k][t][vp] = acc[op + k] + b3[op + k];  // banks (4t+vp)%32 distinct
    __syncthreads();                                   // B1
    #pragma unroll
    for (int k = 0; k < OSTEP; ++k) {
      const float* ar = &adjL[k][uc * ADJ_STRIDE];  // 8 distinct rows/wave, bcast
      const float* xr = &x3L[k][t2][0];             // 8 distinct rows/wave, bcast
      float s = 0.f;
      #pragma unroll
      for (int j = 0; j < 6; ++j) {
        float4 av = *reinterpret_cast<const float4*>(ar + 4 * j);
        float4 xw = *reinterpret_cast<const float4*>(xr + 4 * j);
        s += av.x * xw.x + av.y * xw.y + av.z * xw.z + av.w * xw.w;
      }
      s += ar[24] * xr[24];
      if (act) oL[k][t2][u] = s;
    }
    __syncthreads();                                   // B2
    // coalesced flush: per plane TT*V = 200 floats = 50 float4
    if (tid < OSTEP * 50) {
      const int p = tid / 50, rem = tid - p * 50;
      const int e = rem * 4;
      float4 vv;
      vv.x = oL[p][(e    ) / V_][(e    ) % V_];
      vv.y = oL[p][(e + 1) / V_][(e + 1) % V_];
      vv.z = oL[p][(e + 2) / V_][(e + 2) % V_];
      vv.w = oL[p][(e + 3) / V_][(e + 3) % V_];
      reinterpret_cast<float4*>(outN + (size_t)(op + p) * TV_ + (size_t)t0 * V_)[rem] = vv;
    }
    __syncthreads();                                   // B3
  }
}

// ---------------------------------------------------------------- launch
extern "C" void kernel_launch(void* const* d_in, const int* in_sizes, int n_in,
                              void* d_out, int out_size, void* d_ws, size_t ws_size,
                              hipStream_t stream) {
  const float* x  = (const float*)d_in[0];
  const float* A  = (const float*)d_in[1];
  const float* W1 = (const float*)d_in[2];
  const float* b1 = (const float*)d_in[3];
  const float* W2 = (const float*)d_in[4];
  const float* b2 = (const float*)d_in[5];
  const float* W3 = (const float*)d_in[6];
  const float* b3 = (const float*)d_in[7];
  const float* W4 = (const float*)d_in[8];
  const float* b4 = (const float*)d_in[9];
  const float* W5 = (const float*)d_in[10];
  const float* b5 = (const float*)d_in[11];
  const float* w6 = (const float*)d_in[12];
  const float* b6 = (const float*)d_in[13];
  const float* w7 = (const float*)d_in[14];
  const float* b7 = (const float*)d_in[15];
  float* out = (float*)d_out;

  float* xm   = (float*)d_ws;            // 102,400 f = 0.41 MB
  float* adjP = xm + XM_FLOATS;          // 64*64*700 f = 11.5 MB

  k1_mean<<<dim3(N_ * C_), 256, 0, stream>>>(x, xm);
  k2_adj<<<dim3(N_), 256, 0, stream>>>(xm, A, W1, b1, W2, b2, W4, b4, W5, b5,
                                       w6, b6, w7, b7, adjP);
  kF2<<<dim3(T_ / TT, N_), 256, 0, stream>>>(x, W3, b3, adjP, out);
}